// Round 4
// baseline (1266.662 us; speedup 1.0000x reference)
//
#include <hip/hip_runtime.h>

typedef __bf16 bf16;
typedef __bf16 bf16x4 __attribute__((ext_vector_type(4)));
typedef __bf16 bf16x8 __attribute__((ext_vector_type(8)));
typedef float  f32x4  __attribute__((ext_vector_type(4)));

#define GLD_LDS16(gp, lp) __builtin_amdgcn_global_load_lds( \
    (__attribute__((address_space(1))) void*)(gp),          \
    (__attribute__((address_space(3))) void*)(lp), 16, 0, 0)

// elu(x)+1
__device__ __forceinline__ float e1(float x) { return x > 0.f ? x + 1.f : __expf(x); }

// ---------------------------------------------------------------- LayerNorm: f32 in -> bf16 out
__global__ __launch_bounds__(256) void ln_kernel(const float* __restrict__ x,
                                                 const float* __restrict__ g,
                                                 const float* __restrict__ bb,
                                                 bf16* __restrict__ xn) {
    const int row = blockIdx.x, t = threadIdx.x;
    const float* xr = x + (size_t)row * 1024;
    f32x4 xv = *(const f32x4*)&xr[t * 4];
    float s = xv[0] + xv[1] + xv[2] + xv[3];
    float q = xv[0] * xv[0] + xv[1] * xv[1] + xv[2] * xv[2] + xv[3] * xv[3];
#pragma unroll
    for (int off = 32; off > 0; off >>= 1) {
        s += __shfl_xor(s, off);
        q += __shfl_xor(q, off);
    }
    __shared__ __align__(16) float red[8];
    const int wv = t >> 6, ln2 = t & 63;
    if (ln2 == 0) { red[wv] = s; red[4 + wv] = q; }
    __syncthreads();
    s = red[0] + red[1] + red[2] + red[3];
    q = red[4] + red[5] + red[6] + red[7];
    const float mu = s * (1.f / 1024.f);
    const float var = q * (1.f / 1024.f) - mu * mu;
    const float rs = rsqrtf(var + 1e-5f);
    f32x4 gv = *(const f32x4*)&g[t * 4];
    f32x4 bv = *(const f32x4*)&bb[t * 4];
    bf16x4 ov;
#pragma unroll
    for (int j = 0; j < 4; j++) ov[j] = (bf16)((xv[j] - mu) * rs * gv[j] + bv[j]);
    *(bf16x4*)&xn[(size_t)row * 1024 + t * 4] = ov;
}

// ---------------------------------------------------------------- transpose (f32 src, R x C -> bf16 dst, C x R)
__global__ void transpose_kernel(const float* __restrict__ src, bf16* __restrict__ dst,
                                 int R, int C) {
    __shared__ float tile[32][33];
    const int bx = blockIdx.x * 32, by = blockIdx.y * 32;
    const int tx = threadIdx.x, ty = threadIdx.y;
#pragma unroll
    for (int k2 = 0; k2 < 4; k2++) {
        int y = ty + k2 * 8;
        tile[y][tx] = src[(size_t)(by + y) * C + bx + tx];
    }
    __syncthreads();
#pragma unroll
    for (int k2 = 0; k2 < 4; k2++) {
        int y = ty + k2 * 8;
        dst[(size_t)(bx + y) * R + by + tx] = (bf16)tile[tx][y];
    }
}

// ---------------------------------------------------------------- rope cos/sin table: [4096][32] float2
__global__ void table_kernel(float2* __restrict__ tab) {
    int t = blockIdx.x * 256 + threadIdx.x;   // 131072
    int p = t & 31, n = t >> 5;
    float freq = exp2f(-(float)p * 0.41524101186092030f);  // 10000^(-p/32)
    float ang = (float)n * freq;
    tab[t] = make_float2(cosf(ang), sinf(ang));
}

// ---------------------------------------------------------------- GEMM: C[M][N] = A[M][K] @ Bt[N][K]^T  (bf16 in, CT out)
template <typename CT>
__global__ __launch_bounds__(256) void gemm_bt(const bf16* __restrict__ A,
                                               const bf16* __restrict__ Bt,
                                               CT* __restrict__ C,
                                               int M, int N, int K) {
    __shared__ __align__(16) bf16 sA[128 * 64];
    __shared__ __align__(16) bf16 sB[128 * 64];
    const int tid = threadIdx.x;
    const int wave = tid >> 6, lane = tid & 63;
    const size_t rowBase = (size_t)blockIdx.x * 128;
    const size_t colBase = (size_t)blockIdx.y * 128;
    const int wm = wave >> 1, wn = wave & 1;
    f32x4 acc[4][4];
#pragma unroll
    for (int a = 0; a < 4; a++)
#pragma unroll
        for (int b2 = 0; b2 < 4; b2++) acc[a][b2] = (f32x4){0.f, 0.f, 0.f, 0.f};

    const int r0 = lane >> 3;        // row within 8-row chunk
    const int c0 = (lane & 7) * 8;   // col (elements)
    for (int k0 = 0; k0 < K; k0 += 64) {
#pragma unroll
        for (int i2 = 0; i2 < 4; i2++) {
            const int chunk = wave * 4 + i2;       // 0..15
            const int row = chunk * 8 + r0;        // 0..127
            GLD_LDS16(A + (rowBase + row) * (size_t)K + k0 + c0, sA + chunk * 512);
            GLD_LDS16(Bt + (colBase + row) * (size_t)K + k0 + c0, sB + chunk * 512);
        }
        __syncthreads();
#pragma unroll
        for (int kk = 0; kk < 2; kk++) {
            bf16x8 af[4], bfr[4];
#pragma unroll
            for (int mi = 0; mi < 4; mi++)
                af[mi] = *(const bf16x8*)&sA[(wm * 64 + mi * 16 + (lane & 15)) * 64 + kk * 32 + (lane >> 4) * 8];
#pragma unroll
            for (int ni = 0; ni < 4; ni++)
                bfr[ni] = *(const bf16x8*)&sB[(wn * 64 + ni * 16 + (lane & 15)) * 64 + kk * 32 + (lane >> 4) * 8];
#pragma unroll
            for (int mi = 0; mi < 4; mi++)
#pragma unroll
                for (int ni = 0; ni < 4; ni++)
                    acc[mi][ni] = __builtin_amdgcn_mfma_f32_16x16x32_bf16(af[mi], bfr[ni], acc[mi][ni], 0, 0, 0);
        }
        __syncthreads();
    }
#pragma unroll
    for (int mi = 0; mi < 4; mi++)
#pragma unroll
        for (int ni = 0; ni < 4; ni++)
#pragma unroll
            for (int r = 0; r < 4; r++) {
                size_t row = rowBase + wm * 64 + mi * 16 + (lane >> 4) * 4 + r;
                size_t col = colBase + wn * 64 + ni * 16 + (lane & 15);
                C[row * (size_t)N + col] = (CT)acc[mi][ni][r];
            }
}

// ---------------------------------------------------------------- next_k / next_v: bf16 qkv (b,n,1024*(1|2)+h*64+d) -> f32 (b,h,n,d)
__global__ void copy_kv(const bf16* __restrict__ qkv, float* __restrict__ nk, float* __restrict__ nv) {
    size_t gid = (size_t)blockIdx.x * 256 + threadIdx.x;  // 2 * 2^21
    int which = (int)(gid >> 21);
    size_t r = gid & ((1u << 21) - 1);
    int c = (int)(r & 7), hh = (int)((r >> 3) & 15), n = (int)((r >> 7) & 4095), b2 = (int)(r >> 19);
    const bf16* src = qkv + ((size_t)(b2 * 4096 + n)) * 3072 + 1024 * (which + 1) + hh * 64 + c * 8;
    float* dst = (which ? nv : nk) + (((size_t)(b2 * 16 + hh)) * 4096 + n) * 64 + c * 8;
    bf16x8 v = *(const bf16x8*)src;
    f32x4 lo = {(float)v[0], (float)v[1], (float)v[2], (float)v[3]};
    f32x4 hi = {(float)v[4], (float)v[5], (float)v[6], (float)v[7]};
    *(f32x4*)&dst[0] = lo;
    *(f32x4*)&dst[4] = hi;
}

// ---------------------------------------------------------------- sequential scan over 128 segments
// grid = 128: block = (b,h) x dv-half. 256 threads.
__global__ __launch_bounds__(256) void scan_kernel(const bf16* __restrict__ qkv,
                                                   const float2* __restrict__ tab,
                                                   const float* __restrict__ mem_beta,
                                                   bf16* __restrict__ o) {
    const int blk = blockIdx.x;
    const int bh = blk >> 1, hv = blk & 1;
    const int b = bh >> 4, h = bh & 15;
    const int dvb = hv * 32;
    const int tid = threadIdx.x;

    __shared__ __align__(16) float qs[32][68], ks[32][68], sq[32][68], sk[32][68];  // padded: stride%32 = 4
    __shared__ __align__(16) float vs[32][36], dl[32][36], Pm[32][36];
    __shared__ __align__(16) float memS[64][36];
    __shared__ __align__(16) float zsh[64];

    for (int idx = tid; idx < 64 * 36; idx += 256) (&memS[0][0])[idx] = 0.f;
    if (tid < 64) zsh[tid] = 1e-6f;
    const float beta = 1.f / (1.f + __expf(-mem_beta[h]));
    const float obeta = 1.f - beta;
    const int i8 = tid >> 3, c8 = tid & 7;
    __syncthreads();

    for (int w = 0; w < 128; ++w) {
        const int n0 = w * 32;
        // ---- P0: stage tiles (rope on the fly; elu1 for no-PE q/k; v half)
        {
            const int i = i8, c = c8;
            const size_t rowb = ((size_t)(b * 4096 + n0 + i)) * 3072 + h * 64;
            bf16x8 qv = *(const bf16x8*)&qkv[rowb + c * 8];
            bf16x8 kv = *(const bf16x8*)&qkv[rowb + 1024 + c * 8];
            const float2* trow = tab + (size_t)(n0 + i) * 32 + c * 4;
#pragma unroll
            for (int pp = 0; pp < 4; pp++) {
                float2 cs = trow[pp];
                float q0 = (float)qv[2 * pp], q1 = (float)qv[2 * pp + 1];
                float k0 = (float)kv[2 * pp], k1 = (float)kv[2 * pp + 1];
                qs[i][c * 8 + 2 * pp]     = q0 * cs.x - q1 * cs.y;
                qs[i][c * 8 + 2 * pp + 1] = q1 * cs.x + q0 * cs.y;
                ks[i][c * 8 + 2 * pp]     = k0 * cs.x - k1 * cs.y;
                ks[i][c * 8 + 2 * pp + 1] = k1 * cs.x + k0 * cs.y;
                sq[i][c * 8 + 2 * pp]     = e1(q0);
                sq[i][c * 8 + 2 * pp + 1] = e1(q1);
                sk[i][c * 8 + 2 * pp]     = e1(k0);
                sk[i][c * 8 + 2 * pp + 1] = e1(k1);
            }
            bf16x4 vv = *(const bf16x4*)&qkv[rowb + 2048 + dvb + c * 4];
#pragma unroll
            for (int j2 = 0; j2 < 4; j2++) vs[i][c * 4 + j2] = (float)vv[j2];
        }
        __syncthreads();
        // ---- P1: scores + masked softmax (thread: row i, 4 cols j = jj+8r)
        {
            const int i = i8, jj = c8;
            float s0 = 0.f, s1 = 0.f, s2 = 0.f, s3 = 0.f;
#pragma unroll 4
            for (int d = 0; d < 64; d += 4) {
                f32x4 qv = *(const f32x4*)&qs[i][d];
                f32x4 k0 = *(const f32x4*)&ks[jj][d];
                f32x4 k1 = *(const f32x4*)&ks[jj + 8][d];
                f32x4 k2 = *(const f32x4*)&ks[jj + 16][d];
                f32x4 k3 = *(const f32x4*)&ks[jj + 24][d];
                s0 += qv[0] * k0[0] + qv[1] * k0[1] + qv[2] * k0[2] + qv[3] * k0[3];
                s1 += qv[0] * k1[0] + qv[1] * k1[1] + qv[2] * k1[2] + qv[3] * k1[3];
                s2 += qv[0] * k2[0] + qv[1] * k2[1] + qv[2] * k2[2] + qv[3] * k2[3];
                s3 += qv[0] * k3[0] + qv[1] * k3[1] + qv[2] * k3[2] + qv[3] * k3[3];
            }
            s0 *= 0.125f; s1 *= 0.125f; s2 *= 0.125f; s3 *= 0.125f;
            float mx = -1e30f;
            if (jj <= i) mx = fmaxf(mx, s0);
            if (jj + 8 <= i) mx = fmaxf(mx, s1);
            if (jj + 16 <= i) mx = fmaxf(mx, s2);
            if (jj + 24 <= i) mx = fmaxf(mx, s3);
            mx = fmaxf(mx, __shfl_xor(mx, 1));
            mx = fmaxf(mx, __shfl_xor(mx, 2));
            mx = fmaxf(mx, __shfl_xor(mx, 4));
            float p0 = (jj <= i) ? __expf(s0 - mx) : 0.f;
            float p1 = (jj + 8 <= i) ? __expf(s1 - mx) : 0.f;
            float p2 = (jj + 16 <= i) ? __expf(s2 - mx) : 0.f;
            float p3 = (jj + 24 <= i) ? __expf(s3 - mx) : 0.f;
            float sum = p0 + p1 + p2 + p3;
            sum += __shfl_xor(sum, 1);
            sum += __shfl_xor(sum, 2);
            sum += __shfl_xor(sum, 4);
            const float inv = 1.f / sum;
            Pm[i][jj] = p0 * inv;
            Pm[i][jj + 8] = p1 * inv;
            Pm[i][jj + 16] = p2 * inv;
            Pm[i][jj + 24] = p3 * inv;
        }
        __syncthreads();
        // ---- P2/P3: sdpa, memory read, output, delta (thread: row i, dv chunk c*4)
        {
            const int i = i8, c = c8;
            f32x4 sdp = {0.f, 0.f, 0.f, 0.f};
#pragma unroll 4
            for (int j = 0; j < 32; j++)
                sdp += Pm[i][j] * *(const f32x4*)&vs[j][c * 4];
            f32x4 nm = {0.f, 0.f, 0.f, 0.f}, pv = {0.f, 0.f, 0.f, 0.f};
            float dq = 0.f, dk = 0.f;
#pragma unroll
            for (int kb = 0; kb < 64; kb += 8) {
                const f32x4 a0 = *(const f32x4*)&sq[i][kb], a1 = *(const f32x4*)&sq[i][kb + 4];
                const f32x4 b0 = *(const f32x4*)&sk[i][kb], b1 = *(const f32x4*)&sk[i][kb + 4];
                const f32x4 z0 = *(const f32x4*)&zsh[kb],  z1 = *(const f32x4*)&zsh[kb + 4];
#pragma unroll
                for (int kk = 0; kk < 4; kk++) {
                    const f32x4 m0 = *(const f32x4*)&memS[kb + kk][c * 4];
                    const f32x4 m1 = *(const f32x4*)&memS[kb + 4 + kk][c * 4];
                    nm += a0[kk] * m0; pv += b0[kk] * m0;
                    nm += a1[kk] * m1; pv += b1[kk] * m1;
                    dq += a0[kk] * z0[kk] + a1[kk] * z1[kk];
                    dk += b0[kk] * z0[kk] + b1[kk] * z1[kk];
                }
            }
            const float invdq = 1.f / (dq + 1e-6f);
            const f32x4 vrow = *(const f32x4*)&vs[i][c * 4];
            f32x4 outv = (beta * invdq) * nm + obeta * sdp;
            size_t ob = ((size_t)(b * 4096 + n0 + i)) * 1024 + h * 64 + dvb + c * 4;
            bf16x4 ov;
#pragma unroll
            for (int j2 = 0; j2 < 4; j2++) ov[j2] = (bf16)outv[j2];
            *(bf16x4*)&o[ob] = ov;
            const float invdk = 1.f / dk;
            f32x4 del = vrow - invdk * pv;
            *(f32x4*)&dl[i][c * 4] = del;
        }
        __syncthreads();
        // ---- P4: memory + z update (thread: feature k, dv chunk c2*8)
        {
            const int k = tid >> 2, c2 = tid & 3;
            f32x4 m0 = *(f32x4*)&memS[k][c2 * 8];
            f32x4 m1 = *(f32x4*)&memS[k][c2 * 8 + 4];
            float zacc = 0.f;
#pragma unroll 8
            for (int i = 0; i < 32; i++) {
                float s = sk[i][k];
                f32x4 d0 = *(const f32x4*)&dl[i][c2 * 8];
                f32x4 d1 = *(const f32x4*)&dl[i][c2 * 8 + 4];
                m0 += s * d0; m1 += s * d1;
                zacc += s;
            }
            *(f32x4*)&memS[k][c2 * 8] = m0;
            *(f32x4*)&memS[k][c2 * 8 + 4] = m1;
            if (c2 == 0) zsh[k] += zacc;
        }
        __syncthreads();
    }
}

// ================================================================ launch
extern "C" void kernel_launch(void* const* d_in, const int* in_sizes, int n_in,
                              void* d_out, int out_size, void* d_ws, size_t ws_size,
                              hipStream_t stream) {
    const float* x        = (const float*)d_in[0];
    const float* w_qkv    = (const float*)d_in[1];
    const float* w_out    = (const float*)d_in[2];
    const float* ln_g     = (const float*)d_in[3];
    const float* ln_b     = (const float*)d_in[4];
    const float* mem_beta = (const float*)d_in[5];

    float* out    = (float*)d_out;          // (4,4096,1024) f32
    float* next_k = out + 16777216;         // (4,16,4096,64) f32
    float* next_v = next_k + 16777216;

    char* wsb = (char*)d_ws;
    bf16* xn   = (bf16*)wsb;  wsb += 33554432;   // xn (bf16), later reused as o
    bf16* qkv  = (bf16*)wsb;  wsb += 100663296;  // (16384, 3072) bf16
    bf16* wqT  = (bf16*)wsb;  wsb += 6291456;    // (3072, 1024) bf16
    bf16* woT  = (bf16*)wsb;  wsb += 2097152;    // (1024, 1024) bf16
    float2* tab = (float2*)wsb; wsb += 1048576;  // (4096, 32) cos/sin f32

    ln_kernel<<<16384, 256, 0, stream>>>(x, ln_g, ln_b, xn);
    transpose_kernel<<<dim3(96, 32), dim3(32, 8), 0, stream>>>(w_qkv, wqT, 1024, 3072);
    transpose_kernel<<<dim3(32, 32), dim3(32, 8), 0, stream>>>(w_out, woT, 1024, 1024);
    table_kernel<<<512, 256, 0, stream>>>(tab);
    gemm_bt<bf16><<<dim3(128, 24), 256, 0, stream>>>(xn, wqT, qkv, 16384, 3072, 1024);
    copy_kv<<<16384, 256, 0, stream>>>(qkv, next_k, next_v);
    scan_kernel<<<128, 256, 0, stream>>>(qkv, tab, mem_beta, xn /* o */);
    gemm_bt<float><<<dim3(128, 8), 256, 0, stream>>>(xn, woT, out, 16384, 1024, 1024);
}

// Round 5
// 837.967 us; speedup vs baseline: 1.5116x; 1.5116x over previous
//
#include <hip/hip_runtime.h>

typedef __bf16 bf16;
typedef __bf16 bf16x2 __attribute__((ext_vector_type(2)));
typedef __bf16 bf16x4 __attribute__((ext_vector_type(4)));
typedef __bf16 bf16x8 __attribute__((ext_vector_type(8)));
typedef float  f32x4  __attribute__((ext_vector_type(4)));

#define GLD_LDS16(gp, lp) __builtin_amdgcn_global_load_lds( \
    (__attribute__((address_space(1))) void*)(gp),          \
    (__attribute__((address_space(3))) void*)(lp), 16, 0, 0)

// elu(x)+1
__device__ __forceinline__ float e1(float x) { return x > 0.f ? x + 1.f : __expf(x); }

// ---------------------------------------------------------------- LayerNorm: f32 in -> bf16 out
__global__ __launch_bounds__(256) void ln_kernel(const float* __restrict__ x,
                                                 const float* __restrict__ g,
                                                 const float* __restrict__ bb,
                                                 bf16* __restrict__ xn) {
    const int row = blockIdx.x, t = threadIdx.x;
    const float* xr = x + (size_t)row * 1024;
    f32x4 xv = *(const f32x4*)&xr[t * 4];
    float s = xv[0] + xv[1] + xv[2] + xv[3];
    float q = xv[0] * xv[0] + xv[1] * xv[1] + xv[2] * xv[2] + xv[3] * xv[3];
#pragma unroll
    for (int off = 32; off > 0; off >>= 1) {
        s += __shfl_xor(s, off);
        q += __shfl_xor(q, off);
    }
    __shared__ __align__(16) float red[8];
    const int wv = t >> 6, ln2 = t & 63;
    if (ln2 == 0) { red[wv] = s; red[4 + wv] = q; }
    __syncthreads();
    s = red[0] + red[1] + red[2] + red[3];
    q = red[4] + red[5] + red[6] + red[7];
    const float mu = s * (1.f / 1024.f);
    const float var = q * (1.f / 1024.f) - mu * mu;
    const float rs = rsqrtf(var + 1e-5f);
    f32x4 gv = *(const f32x4*)&g[t * 4];
    f32x4 bv = *(const f32x4*)&bb[t * 4];
    bf16x4 ov;
#pragma unroll
    for (int j = 0; j < 4; j++) ov[j] = (bf16)((xv[j] - mu) * rs * gv[j] + bv[j]);
    *(bf16x4*)&xn[(size_t)row * 1024 + t * 4] = ov;
}

// ---------------------------------------------------------------- transpose (f32 src, R x C -> bf16 dst, C x R)
__global__ void transpose_kernel(const float* __restrict__ src, bf16* __restrict__ dst,
                                 int R, int C) {
    __shared__ float tile[32][33];
    const int bx = blockIdx.x * 32, by = blockIdx.y * 32;
    const int tx = threadIdx.x, ty = threadIdx.y;
#pragma unroll
    for (int k2 = 0; k2 < 4; k2++) {
        int y = ty + k2 * 8;
        tile[y][tx] = src[(size_t)(by + y) * C + bx + tx];
    }
    __syncthreads();
#pragma unroll
    for (int k2 = 0; k2 < 4; k2++) {
        int y = ty + k2 * 8;
        dst[(size_t)(bx + y) * R + by + tx] = (bf16)tile[tx][y];
    }
}

// ---------------------------------------------------------------- rope cos/sin table: [4096][32] float2
__global__ void table_kernel(float2* __restrict__ tab) {
    int t = blockIdx.x * 256 + threadIdx.x;   // 131072
    int p = t & 31, n = t >> 5;
    float freq = exp2f(-(float)p * 0.41524101186092030f);  // 10000^(-p/32)
    float ang = (float)n * freq;
    tab[t] = make_float2(cosf(ang), sinf(ang));
}

// ---------------------------------------------------------------- GEMM: C[M][N] = A[M][K] @ Bt[N][K]^T  (bf16 in, CT out)
template <typename CT>
__global__ __launch_bounds__(256) void gemm_bt(const bf16* __restrict__ A,
                                               const bf16* __restrict__ Bt,
                                               CT* __restrict__ C,
                                               int M, int N, int K) {
    __shared__ __align__(16) bf16 sA[128 * 64];
    __shared__ __align__(16) bf16 sB[128 * 64];
    const int tid = threadIdx.x;
    const int wave = tid >> 6, lane = tid & 63;
    const size_t rowBase = (size_t)blockIdx.x * 128;
    const size_t colBase = (size_t)blockIdx.y * 128;
    const int wm = wave >> 1, wn = wave & 1;
    f32x4 acc[4][4];
#pragma unroll
    for (int a = 0; a < 4; a++)
#pragma unroll
        for (int b2 = 0; b2 < 4; b2++) acc[a][b2] = (f32x4){0.f, 0.f, 0.f, 0.f};

    const int r0 = lane >> 3;        // row within 8-row chunk
    const int c0 = (lane & 7) * 8;   // col (elements)
    for (int k0 = 0; k0 < K; k0 += 64) {
#pragma unroll
        for (int i2 = 0; i2 < 4; i2++) {
            const int chunk = wave * 4 + i2;       // 0..15
            const int row = chunk * 8 + r0;        // 0..127
            GLD_LDS16(A + (rowBase + row) * (size_t)K + k0 + c0, sA + chunk * 512);
            GLD_LDS16(Bt + (colBase + row) * (size_t)K + k0 + c0, sB + chunk * 512);
        }
        __syncthreads();
#pragma unroll
        for (int kk = 0; kk < 2; kk++) {
            bf16x8 af[4], bfr[4];
#pragma unroll
            for (int mi = 0; mi < 4; mi++)
                af[mi] = *(const bf16x8*)&sA[(wm * 64 + mi * 16 + (lane & 15)) * 64 + kk * 32 + (lane >> 4) * 8];
#pragma unroll
            for (int ni = 0; ni < 4; ni++)
                bfr[ni] = *(const bf16x8*)&sB[(wn * 64 + ni * 16 + (lane & 15)) * 64 + kk * 32 + (lane >> 4) * 8];
#pragma unroll
            for (int mi = 0; mi < 4; mi++)
#pragma unroll
                for (int ni = 0; ni < 4; ni++)
                    acc[mi][ni] = __builtin_amdgcn_mfma_f32_16x16x32_bf16(af[mi], bfr[ni], acc[mi][ni], 0, 0, 0);
        }
        __syncthreads();
    }
#pragma unroll
    for (int mi = 0; mi < 4; mi++)
#pragma unroll
        for (int ni = 0; ni < 4; ni++)
#pragma unroll
            for (int r = 0; r < 4; r++) {
                size_t row = rowBase + wm * 64 + mi * 16 + (lane >> 4) * 4 + r;
                size_t col = colBase + wn * 64 + ni * 16 + (lane & 15);
                C[row * (size_t)N + col] = (CT)acc[mi][ni][r];
            }
}

// ---------------------------------------------------------------- next_k / next_v: bf16 qkv (b,n,1024*(1|2)+h*64+d) -> f32 (b,h,n,d)
__global__ void copy_kv(const bf16* __restrict__ qkv, float* __restrict__ nk, float* __restrict__ nv) {
    size_t gid = (size_t)blockIdx.x * 256 + threadIdx.x;  // 2 * 2^21
    int which = (int)(gid >> 21);
    size_t r = gid & ((1u << 21) - 1);
    int c = (int)(r & 7), hh = (int)((r >> 3) & 15), n = (int)((r >> 7) & 4095), b2 = (int)(r >> 19);
    const bf16* src = qkv + ((size_t)(b2 * 4096 + n)) * 3072 + 1024 * (which + 1) + hh * 64 + c * 8;
    float* dst = (which ? nv : nk) + (((size_t)(b2 * 16 + hh)) * 4096 + n) * 64 + c * 8;
    bf16x8 v = *(const bf16x8*)src;
    f32x4 lo = {(float)v[0], (float)v[1], (float)v[2], (float)v[3]};
    f32x4 hi = {(float)v[4], (float)v[5], (float)v[6], (float)v[7]};
    *(f32x4*)&dst[0] = lo;
    *(f32x4*)&dst[4] = hi;
}

// ---------------------------------------------------------------- per-segment causal attention pre-pass
// grid = 64 (b,h) x 128 seg = 8192 blocks, 256 threads. Writes sdpa into o-layout (b,n,h*64+d).
__global__ __launch_bounds__(256) void seg_attn(const bf16* __restrict__ qkv,
                                                const float2* __restrict__ tab,
                                                bf16* __restrict__ o) {
    const int blk = blockIdx.x;
    const int seg = blk & 127, bh = blk >> 7;
    const int b = bh >> 4, h = bh & 15;
    const int n0 = seg * 32;
    const int tid = threadIdx.x;
    const int i = tid >> 3, c = tid & 7;

    __shared__ __align__(16) float qs[32][68], ks[32][68], vs[32][68];
    __shared__ __align__(16) float Pm[32][36];

    // ---- stage: rope q/k, plain v
    {
        const size_t rowb = ((size_t)(b * 4096 + n0 + i)) * 3072 + h * 64;
        bf16x8 qv = *(const bf16x8*)&qkv[rowb + c * 8];
        bf16x8 kv = *(const bf16x8*)&qkv[rowb + 1024 + c * 8];
        bf16x8 vv = *(const bf16x8*)&qkv[rowb + 2048 + c * 8];
        const float2* trow = tab + (size_t)(n0 + i) * 32 + c * 4;
#pragma unroll
        for (int pp = 0; pp < 4; pp++) {
            float2 cs = trow[pp];
            float q0 = (float)qv[2 * pp], q1 = (float)qv[2 * pp + 1];
            float k0 = (float)kv[2 * pp], k1 = (float)kv[2 * pp + 1];
            qs[i][c * 8 + 2 * pp]     = q0 * cs.x - q1 * cs.y;
            qs[i][c * 8 + 2 * pp + 1] = q1 * cs.x + q0 * cs.y;
            ks[i][c * 8 + 2 * pp]     = k0 * cs.x - k1 * cs.y;
            ks[i][c * 8 + 2 * pp + 1] = k1 * cs.x + k0 * cs.y;
            vs[i][c * 8 + 2 * pp]     = (float)vv[2 * pp];
            vs[i][c * 8 + 2 * pp + 1] = (float)vv[2 * pp + 1];
        }
    }
    __syncthreads();
    // ---- scores + masked softmax (thread: row i, 4 cols jj+8r)
    {
        const int jj = c;
        float s0 = 0.f, s1 = 0.f, s2 = 0.f, s3 = 0.f;
#pragma unroll 4
        for (int d = 0; d < 64; d += 4) {
            f32x4 qv = *(const f32x4*)&qs[i][d];
            f32x4 k0 = *(const f32x4*)&ks[jj][d];
            f32x4 k1 = *(const f32x4*)&ks[jj + 8][d];
            f32x4 k2 = *(const f32x4*)&ks[jj + 16][d];
            f32x4 k3 = *(const f32x4*)&ks[jj + 24][d];
            s0 += qv[0] * k0[0] + qv[1] * k0[1] + qv[2] * k0[2] + qv[3] * k0[3];
            s1 += qv[0] * k1[0] + qv[1] * k1[1] + qv[2] * k1[2] + qv[3] * k1[3];
            s2 += qv[0] * k2[0] + qv[1] * k2[1] + qv[2] * k2[2] + qv[3] * k2[3];
            s3 += qv[0] * k3[0] + qv[1] * k3[1] + qv[2] * k3[2] + qv[3] * k3[3];
        }
        s0 *= 0.125f; s1 *= 0.125f; s2 *= 0.125f; s3 *= 0.125f;
        float mx = -1e30f;
        if (jj <= i) mx = fmaxf(mx, s0);
        if (jj + 8 <= i) mx = fmaxf(mx, s1);
        if (jj + 16 <= i) mx = fmaxf(mx, s2);
        if (jj + 24 <= i) mx = fmaxf(mx, s3);
        mx = fmaxf(mx, __shfl_xor(mx, 1));
        mx = fmaxf(mx, __shfl_xor(mx, 2));
        mx = fmaxf(mx, __shfl_xor(mx, 4));
        float p0 = (jj <= i) ? __expf(s0 - mx) : 0.f;
        float p1 = (jj + 8 <= i) ? __expf(s1 - mx) : 0.f;
        float p2 = (jj + 16 <= i) ? __expf(s2 - mx) : 0.f;
        float p3 = (jj + 24 <= i) ? __expf(s3 - mx) : 0.f;
        float sum = p0 + p1 + p2 + p3;
        sum += __shfl_xor(sum, 1);
        sum += __shfl_xor(sum, 2);
        sum += __shfl_xor(sum, 4);
        const float inv = 1.f / sum;
        Pm[i][jj] = p0 * inv;
        Pm[i][jj + 8] = p1 * inv;
        Pm[i][jj + 16] = p2 * inv;
        Pm[i][jj + 24] = p3 * inv;
    }
    __syncthreads();
    // ---- P @ V (thread: row i, dv cols 8c..8c+7) -> write to o layout
    {
        f32x4 a0 = {0.f, 0.f, 0.f, 0.f}, a1 = {0.f, 0.f, 0.f, 0.f};
#pragma unroll 8
        for (int j = 0; j < 32; j++) {
            float p = Pm[i][j];
            a0 += p * *(const f32x4*)&vs[j][c * 8];
            a1 += p * *(const f32x4*)&vs[j][c * 8 + 4];
        }
        bf16x8 ov;
#pragma unroll
        for (int j2 = 0; j2 < 4; j2++) { ov[j2] = (bf16)a0[j2]; ov[4 + j2] = (bf16)a1[j2]; }
        *(bf16x8*)&o[((size_t)(b * 4096 + n0 + i)) * 1024 + h * 64 + c * 8] = ov;
    }
}

// ---------------------------------------------------------------- sequential memory scan (carry-dependent part only)
// grid = 256: block = (b,h) x dv-quarter. 256 threads. In-place RMW on o (sdpa -> final).
__global__ __launch_bounds__(256) void scan2(const bf16* __restrict__ qkv,
                                             const float* __restrict__ mem_beta,
                                             bf16* __restrict__ o) {
    const int blk = blockIdx.x;
    const int cq = blk & 3, bh = blk >> 2;
    const int b = bh >> 4, h = bh & 15;
    const int dvb = cq * 16;
    const int tid = threadIdx.x;
    const int i = tid >> 3, t = tid & 7;

    __shared__ __align__(16) float sq[32][68], sk[32][68];
    __shared__ __align__(16) float memS[64][18];   // 16 cols + 2 pad
    __shared__ __align__(16) float dl[32][18];
    __shared__ __align__(16) float zz[64];

    for (int idx = tid; idx < 64 * 18; idx += 256) (&memS[0][0])[idx] = 0.f;
    if (tid < 64) zz[tid] = 1e-6f;
    const float beta = 1.f / (1.f + __expf(-mem_beta[h]));
    const float obeta = 1.f - beta;

    // prefetch segment 0
    size_t rowq = ((size_t)(b * 4096 + i)) * 3072 + h * 64;
    size_t rowo = ((size_t)(b * 4096 + i)) * 1024 + h * 64 + dvb + 2 * t;
    bf16x8 qreg = *(const bf16x8*)&qkv[rowq + 8 * t];
    bf16x8 kreg = *(const bf16x8*)&qkv[rowq + 1024 + 8 * t];
    bf16x2 vreg = *(const bf16x2*)&qkv[rowq + 2048 + dvb + 2 * t];
    bf16x2 sreg = *(const bf16x2*)&o[rowo];
    __syncthreads();

    for (int w = 0; w < 128; ++w) {
        // ---- stage: elu1(q/k) -> LDS; v/sdpa -> local f32
        float sqr[8], skr[8];
#pragma unroll
        for (int j = 0; j < 8; j++) { sqr[j] = e1((float)qreg[j]); skr[j] = e1((float)kreg[j]); }
        *(f32x4*)&sq[i][8 * t]     = (f32x4){sqr[0], sqr[1], sqr[2], sqr[3]};
        *(f32x4*)&sq[i][8 * t + 4] = (f32x4){sqr[4], sqr[5], sqr[6], sqr[7]};
        *(f32x4*)&sk[i][8 * t]     = (f32x4){skr[0], skr[1], skr[2], skr[3]};
        *(f32x4*)&sk[i][8 * t + 4] = (f32x4){skr[4], skr[5], skr[6], skr[7]};
        const float2 vloc = {(float)vreg[0], (float)vreg[1]};
        const float2 sdloc = {(float)sreg[0], (float)sreg[1]};
        const size_t orow = rowo + (size_t)w * 32768;  // ((w*32) rows) * 1024

        // dens partials from own registers (k in [8t, 8t+8)) with OLD z
        f32x4 z0 = *(const f32x4*)&zz[8 * t];
        f32x4 z1 = *(const f32x4*)&zz[8 * t + 4];
        float dq = sqr[0] * z0[0] + sqr[1] * z0[1] + sqr[2] * z0[2] + sqr[3] * z0[3]
                 + sqr[4] * z1[0] + sqr[5] * z1[1] + sqr[6] * z1[2] + sqr[7] * z1[3];
        float dk = skr[0] * z0[0] + skr[1] * z0[1] + skr[2] * z0[2] + skr[3] * z0[3]
                 + skr[4] * z1[0] + skr[5] * z1[1] + skr[6] * z1[2] + skr[7] * z1[3];

        // issue prefetch for next segment (wraps at w=127; harmless)
        {
            const int wn = (w + 1) & 127;
            const size_t rq = rowq + (size_t)wn * 98304;   // (32 rows)*3072
            qreg = *(const bf16x8*)&qkv[rq + 8 * t];
            kreg = *(const bf16x8*)&qkv[rq + 1024 + 8 * t];
            vreg = *(const bf16x2*)&qkv[rq + 2048 + dvb + 2 * t];
            sreg = *(const bf16x2*)&o[rowo + (size_t)wn * 32768];
        }
        __syncthreads();   // A: sq/sk staged

#pragma unroll
        for (int off = 1; off <= 4; off <<= 1) {
            dq += __shfl_xor(dq, off);
            dk += __shfl_xor(dk, off);
        }

        // num/prev over full k (cols 2t, 2t+1)
        float n0v = 0.f, n1v = 0.f, p0v = 0.f, p1v = 0.f;
#pragma unroll 4
        for (int kb = 0; kb < 64; kb += 4) {
            f32x4 aq = *(const f32x4*)&sq[i][kb];
            f32x4 ak = *(const f32x4*)&sk[i][kb];
#pragma unroll
            for (int j = 0; j < 4; j++) {
                float2 m = *(const float2*)&memS[kb + j][2 * t];
                n0v += aq[j] * m.x; n1v += aq[j] * m.y;
                p0v += ak[j] * m.x; p1v += ak[j] * m.y;
            }
        }
        const float invdq = beta / (dq + 1e-6f);
        const float invdk = 1.f / dk;
        bf16x2 ov;
        ov[0] = (bf16)(n0v * invdq + obeta * sdloc.x);
        ov[1] = (bf16)(n1v * invdq + obeta * sdloc.y);
        *(bf16x2*)&o[orow] = ov;
        *(float2*)&dl[i][2 * t] = make_float2(vloc.x - invdk * p0v, vloc.y - invdk * p1v);
        __syncthreads();   // B: dl ready, all mem reads done

        // ---- update: thread (k2 = tid>>2, c4 = tid&3) owns mem[k2][4c4..4c4+3]
        {
            const int k2 = tid >> 2, c4 = tid & 3;
            f32x4 m4 = *(const f32x4*)&memS[k2][4 * c4];
            float zacc = 0.f;
#pragma unroll 8
            for (int ii = 0; ii < 32; ii++) {
                float s = sk[ii][k2];
                m4 += s * *(const f32x4*)&dl[ii][4 * c4];
                zacc += s;
            }
            *(f32x4*)&memS[k2][4 * c4] = m4;
            if (c4 == 0) zz[k2] += zacc;
        }
        __syncthreads();   // C: mem/z updated
    }
}

// ================================================================ launch
extern "C" void kernel_launch(void* const* d_in, const int* in_sizes, int n_in,
                              void* d_out, int out_size, void* d_ws, size_t ws_size,
                              hipStream_t stream) {
    const float* x        = (const float*)d_in[0];
    const float* w_qkv    = (const float*)d_in[1];
    const float* w_out    = (const float*)d_in[2];
    const float* ln_g     = (const float*)d_in[3];
    const float* ln_b     = (const float*)d_in[4];
    const float* mem_beta = (const float*)d_in[5];

    float* out    = (float*)d_out;          // (4,4096,1024) f32
    float* next_k = out + 16777216;         // (4,16,4096,64) f32
    float* next_v = next_k + 16777216;

    char* wsb = (char*)d_ws;
    bf16* xn   = (bf16*)wsb;  wsb += 33554432;   // xn (bf16) -> later sdpa/o buffer
    bf16* qkv  = (bf16*)wsb;  wsb += 100663296;  // (16384, 3072) bf16
    bf16* wqT  = (bf16*)wsb;  wsb += 6291456;    // (3072, 1024) bf16
    bf16* woT  = (bf16*)wsb;  wsb += 2097152;    // (1024, 1024) bf16
    float2* tab = (float2*)wsb; wsb += 1048576;  // (4096, 32) cos/sin f32

    ln_kernel<<<16384, 256, 0, stream>>>(x, ln_g, ln_b, xn);
    transpose_kernel<<<dim3(96, 32), dim3(32, 8), 0, stream>>>(w_qkv, wqT, 1024, 3072);
    transpose_kernel<<<dim3(32, 32), dim3(32, 8), 0, stream>>>(w_out, woT, 1024, 1024);
    table_kernel<<<512, 256, 0, stream>>>(tab);
    gemm_bt<bf16><<<dim3(128, 24), 256, 0, stream>>>(xn, wqT, qkv, 16384, 3072, 1024);
    copy_kv<<<16384, 256, 0, stream>>>(qkv, next_k, next_v);
    seg_attn<<<8192, 256, 0, stream>>>(qkv, tab, xn /* sdpa into o layout */);
    scan2<<<256, 256, 0, stream>>>(qkv, mem_beta, xn /* in-place: sdpa -> final o */);
    gemm_bt<float><<<dim3(128, 8), 256, 0, stream>>>(xn, woT, out, 16384, 1024, 1024);
}